// Round 5
// baseline (501.309 us; speedup 1.0000x reference)
//
#include <hip/hip_runtime.h>
#include <hip/hip_bf16.h>
#include <stdint.h>

// BitNet-style quantized FFN for MI355X (gfx950).
// Pipeline: absmax(w1,w2) -> scales -> wquant -> LN+actquant ->
//           i8 GEMM1 (+dequant+bias+swish, bf16 out) -> actquant(h) ->
//           i8 GEMM2 (+dequant+bias+mask+residual, fp32 out)
// R5: (a) K-loop restructured: double-buffered LDS, ONE barrier/iter, staging
//     of tile i+1 issued BEFORE compute of tile i -> the vmcnt(0) drain at the
//     barrier is covered by a full compute phase (fixes the m97-style stall;
//     R3/R4 showed tile reshapes don't move the needle because latency, not
//     pipe capacity, binds). BK=64 so 2 buffers fit 48 KB static LDS.
//     (b) zero-division epilogues: inverse scales plumbed through
//     (xdq/hdq/scal[5..6]), swish via v_rcp instead of fp32 div.
//     NB: SQ_LDS_BANK_CONFLICT == 8 cyc x staging-instr count (global_load_lds
//     write occupancy artifact), not read conflicts.

typedef int v4i __attribute__((ext_vector_type(4)));
typedef int v16i __attribute__((ext_vector_type(16)));

__device__ __forceinline__ float wave_max64(float v) {
#pragma unroll
  for (int off = 32; off; off >>= 1) v = fmaxf(v, __shfl_xor(v, off, 64));
  return v;
}

__device__ __forceinline__ void load16_to_lds(const int8_t* g, int8_t* l) {
  __builtin_amdgcn_global_load_lds((const __attribute__((address_space(1))) void*)g,
                                   (__attribute__((address_space(3))) void*)l, 16, 0, 0);
}

// ---------------- per-tensor weight absmax ----------------
__global__ __launch_bounds__(256) void absmax_kernel(const float* __restrict__ w, int n4,
                                                     int* __restrict__ slot) {
  float m = 0.f;
  const float4* w4 = (const float4*)w;
  for (int i = blockIdx.x * 256 + threadIdx.x; i < n4; i += gridDim.x * 256) {
    float4 v = w4[i];
    m = fmaxf(fmaxf(fabsf(v.x), fabsf(v.y)), fmaxf(fmaxf(fabsf(v.z), fabsf(v.w)), m));
  }
  m = wave_max64(m);
  __shared__ float sm[4];
  int lane = threadIdx.x & 63, wv = threadIdx.x >> 6;
  if (!lane) sm[wv] = m;
  __syncthreads();
  if (!threadIdx.x) {
    m = fmaxf(fmaxf(sm[0], sm[1]), fmaxf(sm[2], sm[3]));
    atomicMax(slot, __float_as_int(m));  // nonneg float bits are int-monotone
  }
}

// ---------------- scales: [2]=sw1 [3]=sw2 [4]=qb [5]=wdq1 [6]=wdq2 ----------------
__global__ void scales_kernel(const int* __restrict__ wmax, const int* __restrict__ bits,
                              float* __restrict__ scal) {
  float qb = (float)((1 << (bits[0] - 1)) - 1);
  float m1 = fmaxf(__int_as_float(wmax[0]), 1e-5f);
  float m2 = fmaxf(__int_as_float(wmax[1]), 1e-5f);
  scal[2] = qb / m1;
  scal[3] = qb / m2;
  scal[4] = qb;
  scal[5] = m1 / qb;  // dequant factor for w1
  scal[6] = m2 / qb;  // dequant factor for w2
}

// ---------------- weight quantization to int8 ----------------
__global__ __launch_bounds__(256) void wquant_kernel(const float* __restrict__ w,
                                                     const float* __restrict__ scal, int which,
                                                     int8_t* __restrict__ out) {
  float s = scal[2 + which], qb = scal[4];
  int i = blockIdx.x * 256 + threadIdx.x;
  float4 v = ((const float4*)w)[i];
  char4 q;
  q.x = (char)(int)rintf(fminf(fmaxf(v.x * s, -qb), qb));
  q.y = (char)(int)rintf(fminf(fmaxf(v.y * s, -qb), qb));
  q.z = (char)(int)rintf(fminf(fmaxf(v.z * s, -qb), qb));
  q.w = (char)(int)rintf(fminf(fmaxf(v.w * s, -qb), qb));
  ((char4*)out)[i] = q;
}

// ---------------- fused LayerNorm + per-row int8 absmax quant ----------------
__global__ __launch_bounds__(256) void ln_quant_kernel(const float* __restrict__ x,
                                                       const float* __restrict__ gamma,
                                                       const float* __restrict__ beta,
                                                       int8_t* __restrict__ xq,
                                                       float* __restrict__ xdq) {
  const int row = blockIdx.x;            // 16384 rows, D=1024
  const int tid = threadIdx.x;           // 256 threads x 4 elems
  const float4 v = ((const float4*)(x + (size_t)row * 1024))[tid];
  float s = v.x + v.y + v.z + v.w;
  float ss = fmaf(v.x, v.x, fmaf(v.y, v.y, fmaf(v.z, v.z, v.w * v.w)));
#pragma unroll
  for (int off = 32; off; off >>= 1) {
    s += __shfl_xor(s, off, 64);
    ss += __shfl_xor(ss, off, 64);
  }
  __shared__ float sm[8];
  const int lane = tid & 63, wv = tid >> 6;
  if (!lane) { sm[wv] = s; sm[4 + wv] = ss; }
  __syncthreads();
  s = sm[0] + sm[1] + sm[2] + sm[3];
  ss = sm[4] + sm[5] + sm[6] + sm[7];
  const float mu = s * (1.f / 1024.f);
  const float var = ss * (1.f / 1024.f) - mu * mu;
  const float rstd = rsqrtf(var + 1e-5f);
  const float4 g = ((const float4*)gamma)[tid];
  const float4 bb = ((const float4*)beta)[tid];
  float y0 = (v.x - mu) * rstd * g.x + bb.x;
  float y1 = (v.y - mu) * rstd * g.y + bb.y;
  float y2 = (v.z - mu) * rstd * g.z + bb.z;
  float y3 = (v.w - mu) * rstd * g.w + bb.w;
  float am = fmaxf(fmaxf(fabsf(y0), fabsf(y1)), fmaxf(fabsf(y2), fabsf(y3)));
  am = wave_max64(am);
  __syncthreads();
  if (!lane) sm[wv] = am;
  __syncthreads();
  am = fmaxf(fmaxf(fmaxf(sm[0], sm[1]), fmaxf(sm[2], sm[3])), 1e-5f);
  const float scale = 127.f / am;
  char4 q;
  q.x = (char)(int)rintf(fminf(fmaxf(y0 * scale, -127.f), 127.f));
  q.y = (char)(int)rintf(fminf(fmaxf(y1 * scale, -127.f), 127.f));
  q.z = (char)(int)rintf(fminf(fmaxf(y2 * scale, -127.f), 127.f));
  q.w = (char)(int)rintf(fminf(fmaxf(y3 * scale, -127.f), 127.f));
  ((char4*)(xq + (size_t)row * 1024))[tid] = q;
  if (!tid) xdq[row] = am * (1.f / 127.f);   // dequant factor
}

// ---------------- per-row int8 absmax quant of bf16 h [16384,4096] ----------------
__global__ __launch_bounds__(256) void hquant_kernel(const ushort* __restrict__ h,
                                                     int8_t* __restrict__ hq,
                                                     float* __restrict__ hdq) {
  const int row = blockIdx.x;
  const int tid = threadIdx.x;           // 256 threads x 16 elems
  const int4* p = (const int4*)(h + (size_t)row * 4096);
  union { int4 i4; ushort u[8]; } ua, ub;
  ua.i4 = p[tid * 2];
  ub.i4 = p[tid * 2 + 1];
  float f[16];
#pragma unroll
  for (int i = 0; i < 8; ++i) f[i] = __uint_as_float((unsigned)ua.u[i] << 16);
#pragma unroll
  for (int i = 0; i < 8; ++i) f[8 + i] = __uint_as_float((unsigned)ub.u[i] << 16);
  float am = 0.f;
#pragma unroll
  for (int i = 0; i < 16; ++i) am = fmaxf(am, fabsf(f[i]));
  am = wave_max64(am);
  __shared__ float sm[4];
  const int lane = tid & 63, wv = tid >> 6;
  if (!lane) sm[wv] = am;
  __syncthreads();
  am = fmaxf(fmaxf(fmaxf(sm[0], sm[1]), fmaxf(sm[2], sm[3])), 1e-5f);
  const float scale = 127.f / am;
  union { int4 i4; char c[16]; } q;
#pragma unroll
  for (int i = 0; i < 16; ++i)
    q.c[i] = (char)(int)rintf(fminf(fmaxf(f[i] * scale, -127.f), 127.f));
  ((int4*)(hq + (size_t)row * 4096))[tid] = q.i4;
  if (!tid) hdq[row] = am * (1.f / 127.f);
}

// ---------------- i8 MFMA GEMM core, double-buffered, 1 barrier/iter ----------
// Block tile BMt x BNt, BK=64 B. 4 waves 2x2, wave tile (BMt/2)x(BNt/2),
// frags AM x AN of 32x32x32. LDS rows 64 B; k-chunk s of row r stored at
// physical slot s^(r&3) (swizzle via global-fetch addressing; global_load_lds
// dest is wave-uniform base + lane*16).
// Loop: sync; stage(i+1 -> buf[(i+1)&1]); compute(i, buf[i&1]).
// The barrier's vmcnt(0) drain covers loads issued one full compute earlier.
template <int K, int BMt, int BNt>
__device__ __forceinline__ void gemm_core(const int8_t* __restrict__ A,
                                          const int8_t* __restrict__ B, int8_t* As, int8_t* Bs,
                                          v16i (&acc)[BMt / 64][BNt / 64]) {
  constexpr int AM = BMt / 64, AN = BNt / 64;
  constexpr int NI = K / 64;
  const int tid = threadIdx.x;
  const int lane = tid & 63;
  const int wave = tid >> 6;
  const int wm = (wave & 1) * (BMt / 2);
  const int wn = (wave >> 1) * (BNt / 2);
  const int lrow = lane & 31;
  const int half = lane >> 5;
  const int x3 = lrow & 3;
  const size_t m0 = (size_t)blockIdx.y * BMt;
  const size_t n0 = (size_t)blockIdx.x * BNt;

  // staging: thread handles chunk (tid + t*256); row r = tid>>2 (+64 per t,
  // preserves r&3); global chunk = phys_slot ^ (r&3)
  const int r = tid >> 2;
  const int cs = ((tid & 3) ^ (r & 3)) << 4;
  const int8_t* ga = A + (m0 + r) * K + cs;
  const int8_t* gb = B + (n0 + r) * K + cs;

  auto stage = [&](int k0, int bi) {
    int8_t* la = As + bi * (BMt * 64) + tid * 16;
    int8_t* lb = Bs + bi * (BNt * 64) + tid * 16;
#pragma unroll
    for (int t = 0; t < BMt / 64; ++t)
      load16_to_lds(ga + (size_t)(t * 64) * K + k0, la + t * 4096);
#pragma unroll
    for (int t = 0; t < BNt / 64; ++t)
      load16_to_lds(gb + (size_t)(t * 64) * K + k0, lb + t * 4096);
  };

  stage(0, 0);
  for (int i = 0; i < NI; ++i) {
    __syncthreads();                 // stage(i) visible; buf[(i+1)&1] free
    if (i + 1 < NI) stage((i + 1) * 64, (i + 1) & 1);
    const int8_t* Ab = As + (i & 1) * (BMt * 64);
    const int8_t* Bb = Bs + (i & 1) * (BNt * 64);
#pragma unroll
    for (int ks = 0; ks < 2; ++ks) {
      const int so = ((ks * 2 + half) ^ x3) << 4;
      v4i af[AM], bf[AN];
#pragma unroll
      for (int ii = 0; ii < AM; ++ii)
        af[ii] = *(const v4i*)(Ab + (wm + ii * 32 + lrow) * 64 + so);
#pragma unroll
      for (int j = 0; j < AN; ++j)
        bf[j] = *(const v4i*)(Bb + (wn + j * 32 + lrow) * 64 + so);
#pragma unroll
      for (int ii = 0; ii < AM; ++ii)
#pragma unroll
        for (int j = 0; j < AN; ++j)
          acc[ii][j] = __builtin_amdgcn_mfma_i32_32x32x32_i8(af[ii], bf[j], acc[ii][j], 0, 0, 0);
    }
  }
}

// ---------------- GEMM1: C=xq@w1q^T, dequant+bias+swish -> bf16 h ----------------
// 128x256 tile, dbuf: As 2x8K, Bs 2x16K = 48 KB
__global__ __launch_bounds__(256, 2) void gemm1_kernel(const int8_t* __restrict__ Aq,
                                                       const int8_t* __restrict__ Bq,
                                                       const float* __restrict__ xdq,
                                                       const float* __restrict__ scal,
                                                       const float* __restrict__ bias,
                                                       ushort* __restrict__ H) {
  __shared__ __align__(16) int8_t As[2 * 128 * 64];
  __shared__ __align__(16) int8_t Bs[2 * 256 * 64];
  v16i acc[2][4] = {};
  gemm_core<1024, 128, 256>(Aq, Bq, As, Bs, acc);
  const float wdq = scal[5];
  const int lane = threadIdx.x & 63;
  const int wave = threadIdx.x >> 6;
  const int m0 = blockIdx.y * 128 + (wave & 1) * 64;
  const int n0 = blockIdx.x * 256 + (wave >> 1) * 128;
  const int cn = lane & 31;
  const int h4 = (lane >> 5) << 2;
#pragma unroll
  for (int i = 0; i < 2; ++i) {
#pragma unroll
    for (int reg = 0; reg < 16; ++reg) {
      const int row = (reg & 3) + ((reg >> 2) << 3) + h4;  // C/D layout (m74/m101)
      const int m = m0 + i * 32 + row;
      const float dq = xdq[m] * wdq;
#pragma unroll
      for (int j = 0; j < 4; ++j) {
        const int n = n0 + j * 32 + cn;
        const float v = fmaf((float)acc[i][j][reg], dq, bias[n]);
        const float hsw = v * __builtin_amdgcn_rcpf(1.0f + __expf(-v));  // swish, no div
        __hip_bfloat16 hb = __float2bfloat16(hsw);
        H[(size_t)m * 4096 + n] = *(const ushort*)&hb;
      }
    }
  }
}

// ---------------- GEMM2: C=hq@w2q^T, dequant+bias+mask+residual -> fp32 out ----------------
// 256x128 tile, dbuf: As 2x16K, Bs 2x8K = 48 KB
__global__ __launch_bounds__(256, 2) void gemm2_kernel(const int8_t* __restrict__ Aq,
                                                       const int8_t* __restrict__ Bq,
                                                       const float* __restrict__ hdq,
                                                       const float* __restrict__ scal,
                                                       const float* __restrict__ bias,
                                                       const float* __restrict__ x,
                                                       const float* __restrict__ mask,
                                                       float* __restrict__ out) {
  __shared__ __align__(16) int8_t As[2 * 256 * 64];
  __shared__ __align__(16) int8_t Bs[2 * 128 * 64];
  v16i acc[4][2] = {};
  gemm_core<4096, 256, 128>(Aq, Bq, As, Bs, acc);
  const float wdq = scal[6];
  const int lane = threadIdx.x & 63;
  const int wave = threadIdx.x >> 6;
  const int m0 = blockIdx.y * 256 + (wave & 1) * 128;
  const int n0 = blockIdx.x * 128 + (wave >> 1) * 64;
  const int cn = lane & 31;
  const int h4 = (lane >> 5) << 2;
#pragma unroll
  for (int i = 0; i < 4; ++i) {
#pragma unroll
    for (int reg = 0; reg < 16; ++reg) {
      const int row = (reg & 3) + ((reg >> 2) << 3) + h4;
      const int m = m0 + i * 32 + row;
      const float dq = hdq[m] * wdq;
      const float mk = 0.5f * mask[m];
#pragma unroll
      for (int j = 0; j < 2; ++j) {
        const int n = n0 + j * 32 + cn;
        const float v = fmaf((float)acc[i][j][reg], dq, bias[n]);
        const size_t idx = (size_t)m * 1024 + n;
        out[idx] = fmaf(mk, v, x[idx]);
      }
    }
  }
}

extern "C" void kernel_launch(void* const* d_in, const int* in_sizes, int n_in, void* d_out,
                              int out_size, void* d_ws, size_t ws_size, hipStream_t stream) {
  const float* x = (const float*)d_in[0];      // [8,2048,1024]
  const float* mask = (const float*)d_in[1];   // [8,2048,1]
  const float* gamma = (const float*)d_in[2];  // [1024]
  const float* beta = (const float*)d_in[3];   // [1024]
  const float* w1 = (const float*)d_in[4];     // [4096,1024]
  const float* b1 = (const float*)d_in[5];     // [4096]
  const float* w2 = (const float*)d_in[6];     // [1024,4096]
  const float* b2 = (const float*)d_in[7];     // [1024]
  const int* bits = (const int*)d_in[8];       // scalar
  float* out = (float*)d_out;

  char* ws = (char*)d_ws;
  int* wmax = (int*)ws;                              // slots [0],[1]
  float* scal = (float*)ws;                          // [2..6]
  float* xdq = (float*)(ws + (1u << 20));            // 16384 f32 (dequant factors)
  float* hdq = (float*)(ws + (2u << 20));            // 16384 f32
  int8_t* w1q = (int8_t*)(ws + (4u << 20));          // 4 MB
  int8_t* w2q = (int8_t*)(ws + (8u << 20));          // 4 MB
  int8_t* xq = (int8_t*)(ws + (12u << 20));          // 16 MB
  int8_t* hq = (int8_t*)(ws + (28u << 20));          // 64 MB
  ushort* h = (ushort*)(ws + (size_t)(92u << 20));   // 128 MB bf16

  const int NW = 4096 * 1024;  // elements per weight matrix

  absmax_kernel<<<1024, 256, 0, stream>>>(w1, NW / 4, wmax + 0);
  absmax_kernel<<<1024, 256, 0, stream>>>(w2, NW / 4, wmax + 1);
  scales_kernel<<<1, 1, 0, stream>>>(wmax, bits, scal);
  wquant_kernel<<<NW / 1024, 256, 0, stream>>>(w1, scal, 0, w1q);
  wquant_kernel<<<NW / 1024, 256, 0, stream>>>(w2, scal, 1, w2q);
  ln_quant_kernel<<<16384, 256, 0, stream>>>(x, gamma, beta, xq, xdq);
  gemm1_kernel<<<dim3(4096 / 256, 16384 / 128), 256, 0, stream>>>(xq, w1q, xdq, scal, b1, h);
  hquant_kernel<<<16384, 256, 0, stream>>>(h, hq, hdq);
  gemm2_kernel<<<dim3(1024 / 128, 16384 / 256), 256, 0, stream>>>(hq, w2q, hdq, scal, b2, x,
                                                                  mask, out);
}